// Round 10
// baseline (127.561 us; speedup 1.0000x reference)
//
#include <hip/hip_runtime.h>
#include <stdint.h>

// ---------------------------------------------------------------------------
// Fused MHA forward: B=2, S=2048, E=1024, H=16, D=64, fp32 in/out,
// bf16 MFMA compute internally. Exact (max-free) softmax: Q,K are LayerNorm'd
// so |score|*log2e <= ~23 -> exp2 never overflows; softmax is shift-invariant.
// GEMM1 (QKV+LN) = 256^2 tile, 8 waves, tri-buffered LDS, counted vmcnt(4)
// gates (T3+T4: loads in flight across barriers, never drained to 0),
// setprio'd 16-MFMA clusters. attn / gemm_out / cvt / combine = R9 proven.
// ---------------------------------------------------------------------------

typedef __bf16 bf16_t;
typedef __bf16 bf16x8 __attribute__((ext_vector_type(8)));
typedef __bf16 bf16x4 __attribute__((ext_vector_type(4)));
typedef __bf16 bf16x2 __attribute__((ext_vector_type(2)));
typedef float f32x4 __attribute__((ext_vector_type(4)));
typedef float f32x16 __attribute__((ext_vector_type(16)));
typedef uint32_t u32x4 __attribute__((ext_vector_type(4)));

#define S_LEN 2048
#define QSCALE 0.1803368801f   // 0.125 * log2(e), folded into Q at GEMM1

__device__ __forceinline__ void load_lds16(const void* g, void* l) {
  __builtin_amdgcn_global_load_lds((__attribute__((address_space(1))) void*)g,
                                   (__attribute__((address_space(3))) void*)l,
                                   16, 0, 0);
}

__device__ __forceinline__ f32x4 mfma16(bf16x8 a, bf16x8 b, f32x4 c) {
  return __builtin_amdgcn_mfma_f32_16x16x32_bf16(a, b, c, 0, 0, 0);
}

__device__ __forceinline__ f32x16 mfma32(bf16x8 a, bf16x8 b, f32x16 c) {
  return __builtin_amdgcn_mfma_f32_32x32x16_bf16(a, b, c, 0, 0, 0);
}

__device__ __forceinline__ uint32_t pk_bf16(float a, float b) {
  bf16x2 v; v[0] = (bf16_t)a; v[1] = (bf16_t)b;
  return __builtin_bit_cast(uint32_t, v);
}

__device__ __forceinline__ void plswap(uint32_t& a, uint32_t& b) {
  asm volatile("v_permlane32_swap_b32 %0, %1" : "+v"(a), "+v"(b));
}

// ---------------- fp32 -> bf16 convert, all tensors in one launch ----------
__global__ void cvt_all(const float* __restrict__ x, const float* __restrict__ Wq,
                        const float* __restrict__ Wk, const float* __restrict__ Wv,
                        const float* __restrict__ Wo,
                        bf16_t* __restrict__ xb, bf16_t* __restrict__ Wb,
                        bf16_t* __restrict__ Wob) {
  const int bid = blockIdx.x;
  const float* src; bf16_t* dst; int idx;
  if (bid < 4096) { src = x; dst = xb; idx = bid; }
  else {
    const int r = bid - 4096, rg = r >> 10;
    idx = r & 1023;
    if (rg == 0)      { src = Wq; dst = Wb; }
    else if (rg == 1) { src = Wk; dst = Wb + (1 << 20); }
    else if (rg == 2) { src = Wv; dst = Wb + (2 << 20); }
    else              { src = Wo; dst = Wob; }
  }
  const int i = (idx * 256 + threadIdx.x) * 4;
  float4 v = *reinterpret_cast<const float4*>(src + i);
  bf16x4 o;
  o[0] = (bf16_t)v.x; o[1] = (bf16_t)v.y; o[2] = (bf16_t)v.z; o[3] = (bf16_t)v.w;
  *reinterpret_cast<bf16x4*>(dst + i) = o;
}

// ---------------- GEMM1: QKV projection + bias + per-head LN ----------------
// 256x256 tile, BK=32, 8 waves (2Mx4N, 128x64 each), tri-buffer LDS (96KB),
// counted vmcnt(4) gate per K-tile (prefetch lead = 2 tiles). LDS layout per
// operand half [128 rows][4 ch of 8 elems]: elem = ch*1024 + row*8 -> wave
// fragment reads are contiguous (conflict-free); global_load_lds dest linear.
__launch_bounds__(512, 2)
__global__ void gemm_qkv_ln(const bf16_t* __restrict__ A, const bf16_t* __restrict__ Bt,
                            const float* __restrict__ bq, const float* __restrict__ bk,
                            const float* __restrict__ bv,
                            const float* __restrict__ qnw, const float* __restrict__ qnb,
                            const float* __restrict__ knw, const float* __restrict__ knb,
                            bf16_t* __restrict__ Qb, bf16_t* __restrict__ Kb,
                            bf16_t* __restrict__ Vt) {
  __shared__ alignas(16) bf16_t S[3 * 16384];   // 96 KB: 3 bufs x [A 8192 | B 8192]
  const int t = threadIdx.x;
  const int wid = t >> 6, lane = t & 63;
  const int wr = wid >> 2, wcn = wid & 3;       // 2 M-waves x 4 N-waves
  const int lg = lane >> 4, lr = lane & 15;
  const int orig = blockIdx.x;                  // 192 blocks (16 bm x 12 bn)
  const int swz = (orig & 7) * 24 + (orig >> 3);
  const int bm = swz / 12, bn = swz % 12;

  const bf16_t* gA = A + (size_t)(bm * 256 + (t & 127)) * 1024 + ((t >> 7) << 3);
  const bf16_t* gB = Bt + (size_t)(bn * 256 + (t & 127)) * 1024 + ((t >> 7) << 3);

  f32x4 acc[8][4] = {};
  bf16x8 bfr[4], af[4];

  const int aoff = wr * 4096 + lg * 1024 + lr * 8;                          // + mt*128
  const int boff = 8192 + (wcn >> 1) * 4096 + lg * 1024 + (wcn & 1) * 512 + lr * 8;  // + nt*128

#define ST(bufx, ktx, op, hh)                                                  \
  load_lds16(((op) ? gB : gA) + (hh) * 131072 + (ktx) * 32,                    \
             &S[(bufx) * 16384 + (op) * 8192 + (hh) * 4096 + t * 8])

  // prologue: tile 0 -> buf0, tile 1 -> buf1 (4 loads each)
  ST(0, 0, 0, 0); ST(0, 0, 0, 1); ST(0, 0, 1, 0); ST(0, 0, 1, 1);
  ST(1, 1, 0, 0); ST(1, 1, 0, 1); ST(1, 1, 1, 0); ST(1, 1, 1, 1);

  int buf = 0, buf2 = 2;
  for (int kt = 0; kt < 32; ++kt) {
    const int ks2 = (kt + 2 < 32) ? kt + 2 : 31;   // clamp keeps vmcnt math uniform
    const int sbase = buf * 16384;
    // ---- sub-phase 0 (mt 0..3) : gate on this K-tile's 4 loads ----
    asm volatile("s_waitcnt vmcnt(4)" ::: "memory");
    __builtin_amdgcn_sched_barrier(0);
    __builtin_amdgcn_s_barrier();
    __builtin_amdgcn_sched_barrier(0);
#pragma unroll
    for (int nt = 0; nt < 4; ++nt)
      bfr[nt] = *reinterpret_cast<const bf16x8*>(&S[sbase + boff + nt * 128]);
#pragma unroll
    for (int m2 = 0; m2 < 4; ++m2)
      af[m2] = *reinterpret_cast<const bf16x8*>(&S[sbase + aoff + m2 * 128]);
    ST(buf2, ks2, 0, 0);
    ST(buf2, ks2, 0, 1);
    __builtin_amdgcn_s_barrier();
    asm volatile("s_waitcnt lgkmcnt(0)" ::: "memory");
    __builtin_amdgcn_sched_barrier(0);
    __builtin_amdgcn_s_setprio(1);
#pragma unroll
    for (int m2 = 0; m2 < 4; ++m2)
#pragma unroll
      for (int nt = 0; nt < 4; ++nt)
        acc[m2][nt] = mfma16(af[m2], bfr[nt], acc[m2][nt]);
    __builtin_amdgcn_s_setprio(0);
    __builtin_amdgcn_s_barrier();
    // ---- sub-phase 1 (mt 4..7) ----
#pragma unroll
    for (int m2 = 0; m2 < 4; ++m2)
      af[m2] = *reinterpret_cast<const bf16x8*>(&S[sbase + aoff + (4 + m2) * 128]);
    ST(buf2, ks2, 1, 0);
    ST(buf2, ks2, 1, 1);
    __builtin_amdgcn_s_barrier();
    asm volatile("s_waitcnt lgkmcnt(0)" ::: "memory");
    __builtin_amdgcn_sched_barrier(0);
    __builtin_amdgcn_s_setprio(1);
#pragma unroll
    for (int m2 = 0; m2 < 4; ++m2)
#pragma unroll
      for (int nt = 0; nt < 4; ++nt)
        acc[4 + m2][nt] = mfma16(af[m2], bfr[nt], acc[4 + m2][nt]);
    __builtin_amdgcn_s_setprio(0);
    __builtin_amdgcn_s_barrier();
    buf = (buf == 2) ? 0 : buf + 1;
    buf2 = (buf2 == 2) ? 0 : buf2 + 1;
  }
#undef ST

  const int nbase = bn * 256 + wcn * 64;   // one head per wave (256 | 1024 align)
  const int region = nbase >> 10;          // 0=Q 1=K 2=V (uniform per block)
  const int h = (nbase & 1023) >> 6;

  if (region == 2) {
    // V epilogue: per-wave LDS transpose (2 batches of 64 s-rows), 16B stores
    __syncthreads();
    char* Vb = reinterpret_cast<char*>(&S[wid * 4096]);   // 8KB per wave
    const int s0g = bm * 256 + wr * 128;
    const int bb = s0g >> 11;
    const int sl = s0g & 2047;
#pragma unroll
    for (int bt = 0; bt < 2; ++bt) {
#pragma unroll
      for (int m3 = 0; m3 < 4; ++m3) {
        const int mt = bt * 4 + m3;
#pragma unroll
        for (int nt = 0; nt < 4; ++nt) {
          const int d = nt * 16 + lr;
          const float bvd = bv[h * 64 + d];
          const int slot = (m3 * 2 + (lg >> 1)) ^ (d & 7);
          uint2 pr;
          pr.x = pk_bf16(acc[mt][nt][0] + bvd, acc[mt][nt][1] + bvd);
          pr.y = pk_bf16(acc[mt][nt][2] + bvd, acc[mt][nt][3] + bvd);
          *reinterpret_cast<uint2*>(Vb + d * 128 + slot * 16 + (lg & 1) * 8) = pr;
        }
      }
      asm volatile("s_waitcnt lgkmcnt(0)" ::: "memory");
      __builtin_amdgcn_sched_barrier(0);
#pragma unroll
      for (int it2 = 0; it2 < 8; ++it2) {
        const int d = it2 * 8 + (lane >> 3);
        const int ch = lane & 7;
        bf16x8 vv8 = *reinterpret_cast<const bf16x8*>(Vb + d * 128 + ((ch ^ (d & 7)) << 4));
        *reinterpret_cast<bf16x8*>(
            Vt + (((size_t)((bb * 16 + h) * 64 + d)) << 11) + sl + bt * 64 + ch * 8) = vv8;
      }
      if (bt == 0) {
        asm volatile("s_waitcnt lgkmcnt(0)" ::: "memory");
        __builtin_amdgcn_sched_barrier(0);
      }
    }
  } else {
    const float* bias = region ? bk : bq;
    const float* lw = region ? knw : qnw;
    const float* lb = region ? knb : qnb;
    const float osc = region ? 1.0f : QSCALE;
    bf16_t* Outp = region ? Kb : Qb;
#pragma unroll
    for (int mt = 0; mt < 8; ++mt)
#pragma unroll
      for (int r = 0; r < 4; ++r) {
        const int gm = bm * 256 + wr * 128 + mt * 16 + lg * 4 + r;
        const int b = gm >> 11, s = gm & 2047;
        float vv[4], sum = 0.f, sumsq = 0.f;
#pragma unroll
        for (int nt = 0; nt < 4; ++nt) {
          const int d = nt * 16 + lr;
          vv[nt] = acc[mt][nt][r] + bias[h * 64 + d];
          sum += vv[nt];
          sumsq += vv[nt] * vv[nt];
        }
#pragma unroll
        for (int mk = 1; mk < 16; mk <<= 1) {
          sum += __shfl_xor(sum, mk);
          sumsq += __shfl_xor(sumsq, mk);
        }
        const float mean = sum * (1.f / 64.f);
        const float var = sumsq * (1.f / 64.f) - mean * mean;
        const float rstd = rsqrtf(var + 1e-5f);
        const size_t rowoff = ((size_t)((b * 16 + h) * 2048 + s)) << 6;
#pragma unroll
        for (int nt = 0; nt < 4; ++nt) {
          const int d = nt * 16 + lr;
          float y = ((vv[nt] - mean) * rstd * lw[d] + lb[d]) * osc;
          Outp[rowoff + d] = (bf16_t)y;
        }
      }
  }
}

// ---------------- GEMM2: output projection, 64x128 tile, 2-phase dbuf -------
__launch_bounds__(256, 2)
__global__ void gemm_out(const bf16_t* __restrict__ A, const bf16_t* __restrict__ Bt,
                         const float* __restrict__ bo, float* __restrict__ dout) {
  __shared__ alignas(16) bf16_t As[2][64 * 32];
  __shared__ alignas(16) bf16_t Bs[2][128 * 32];
  const int t = threadIdx.x;
  const int orig = blockIdx.y * 8 + blockIdx.x;           // 512 blocks
  const int logical = (orig & 7) * 64 + (orig >> 3);
  const int bn = logical & 7, bm = logical >> 3;
  const int w = t >> 6, lane = t & 63;
  const int wr = w >> 1, wc = w & 1;                      // wave tile 32x64
  const int lg = lane >> 4, lr = lane & 15;

  f32x4 acc[2][4] = {};
  const int srow = t >> 2;
  const int scol = (t & 3) << 3;
  const bf16_t* ga = A + ((size_t)(bm * 64 + srow) << 10) + scol;
  const bf16_t* gb = Bt + ((size_t)(bn * 128 + srow) << 10) + scol;

#define OSTAGE(buf, k0)                                        \
  {                                                            \
    load_lds16(ga + (k0),         &As[buf][t * 8]);            \
    load_lds16(gb + (k0),         &Bs[buf][t * 8]);            \
    load_lds16(gb + 65536 + (k0), &Bs[buf][2048 + t * 8]);     \
  }

  OSTAGE(0, 0);
  __syncthreads();
  for (int it = 0; it < 32; ++it) {
    const int cur = it & 1;
    if (it < 31) OSTAGE(cur ^ 1, (it + 1) << 5);
    bf16x8 af[2], bfr[4];
#pragma unroll
    for (int mt = 0; mt < 2; ++mt)
      af[mt] = *reinterpret_cast<const bf16x8*>(&As[cur][((wr * 32 + mt * 16 + lr) << 5) + lg * 8]);
#pragma unroll
    for (int nt = 0; nt < 4; ++nt)
      bfr[nt] = *reinterpret_cast<const bf16x8*>(&Bs[cur][((wc * 64 + nt * 16 + lr) << 5) + lg * 8]);
#pragma unroll
    for (int mt = 0; mt < 2; ++mt)
#pragma unroll
      for (int nt = 0; nt < 4; ++nt)
        acc[mt][nt] = mfma16(af[mt], bfr[nt], acc[mt][nt]);
    __syncthreads();
  }
#undef OSTAGE

#pragma unroll
  for (int mt = 0; mt < 2; ++mt)
#pragma unroll
    for (int r = 0; r < 4; ++r) {
      const int gm = bm * 64 + wr * 32 + mt * 16 + lg * 4 + r;
#pragma unroll
      for (int nt = 0; nt < 4; ++nt) {
        const int gn = bn * 128 + wc * 64 + nt * 16 + lr;
        dout[((size_t)gm << 10) + gn] = acc[mt][nt][r] + bo[gn];
      }
    }
}

// ---------------- flash attention, max-free softmax ----------
template <int NSPLIT>
__launch_bounds__(256, 4)
__global__ void attn_kernel(const bf16_t* __restrict__ Qb, const bf16_t* __restrict__ Kb,
                            const bf16_t* __restrict__ Vt, bf16_t* __restrict__ Og,
                            bf16_t* __restrict__ Op, float* __restrict__ Lp) {
  __shared__ alignas(16) bf16_t KVs[4][64 * 64];  // [0..1]=K dbuf, [2..3]=V dbuf

  const int t = threadIdx.x;
  const int w = t >> 6, lane = t & 63;
  const int lq = lane & 31;
  const int hi = lane >> 5;
  const int orig = (blockIdx.z * 32 + blockIdx.y) * 16 + blockIdx.x;
  const int logical = (orig & 7) * (64 * NSPLIT) + (orig >> 3);  // XCD-contig
  const int qt = logical & 15;
  const int bh = (logical >> 4) & 31;
  const int z = (NSPLIT == 1) ? 0 : (logical >> 9);
  const int b = bh >> 4, h = bh & 15;
  const int q0 = qt * 128 + w * 32;
  const int ntiles = 32 / NSPLIT;

  bf16x8 qf[4];   // Q pre-scaled by QSCALE in GEMM1
  {
    const bf16_t* qp = Qb + (((size_t)bh * S_LEN + q0 + lq) << 6) + hi * 8;
#pragma unroll
    for (int c = 0; c < 4; ++c)
      qf[c] = *reinterpret_cast<const bf16x8*>(qp + c * 16);
  }

  f32x16 oacc0 = {}, oacc1 = {}, lacc = {};

  const int krow = (t >> 1) & 63;
  const int kch = ((t >> 7) << 1) | (t & 1);
  const bf16_t* kbase = Kb + (((size_t)bh * S_LEN) << 6) + krow * 64 + kch * 8;
  const bf16_t* vbase = Vt + ((size_t)bh << 17) + krow * S_LEN + kch * 8;

#define STAGE(buf, jt)                                                       \
  {                                                                          \
    const bf16_t* kb_ = kbase + (((size_t)(jt)) << 12);                      \
    const bf16_t* vb_ = vbase + (jt) * 64;                                   \
    load_lds16(kb_,      &KVs[buf][t * 8]);                                  \
    load_lds16(kb_ + 32, &KVs[buf][2048 + t * 8]);                           \
    load_lds16(vb_,      &KVs[2 + (buf)][t * 8]);                            \
    load_lds16(vb_ + 32, &KVs[2 + (buf)][2048 + t * 8]);                     \
  }

  STAGE(0, z * ntiles);
  __syncthreads();

  for (int j = 0; j < ntiles; ++j) {
    const int cur = j & 1;
    if (j < ntiles - 1) STAGE(cur ^ 1, z * ntiles + j + 1);

    f32x16 s0 = {}, s1 = {};
    const bf16_t* kr = &KVs[cur][lq * 16 + hi * 8];
    __builtin_amdgcn_s_setprio(1);
#pragma unroll
    for (int c = 0; c < 4; ++c) {
      bf16x8 kf = *reinterpret_cast<const bf16x8*>(kr + c * 1024);
      s0 = mfma32(kf, qf[c], s0);
    }
#pragma unroll
    for (int c = 0; c < 4; ++c) {
      bf16x8 kf = *reinterpret_cast<const bf16x8*>(kr + 512 + c * 1024);
      s1 = mfma32(kf, qf[c], s1);
    }
    __builtin_amdgcn_s_setprio(0);

    f32x16 p0, p1;
#pragma unroll
    for (int i = 0; i < 16; ++i) p0[i] = __builtin_amdgcn_exp2f(s0[i]);
#pragma unroll
    for (int i = 0; i < 16; ++i) p1[i] = __builtin_amdgcn_exp2f(s1[i]);
    lacc += p0;
    lacc += p1;

    const bf16_t* vr = &KVs[2 + cur][lq * 16 + hi * 8];
    __builtin_amdgcn_s_setprio(1);
#pragma unroll
    for (int c = 0; c < 4; ++c) {
      const f32x16 ph = (c < 2) ? p0 : p1;
      const int cl = c & 1;
      uint32_t w00 = pk_bf16(ph[8 * cl + 0], ph[8 * cl + 1]);
      uint32_t w01 = pk_bf16(ph[8 * cl + 2], ph[8 * cl + 3]);
      uint32_t w10 = pk_bf16(ph[8 * cl + 4], ph[8 * cl + 5]);
      uint32_t w11 = pk_bf16(ph[8 * cl + 6], ph[8 * cl + 7]);
      plswap(w00, w10);
      plswap(w01, w11);
      u32x4 pw = {w00, w01, w10, w11};
      bf16x8 pf = __builtin_bit_cast(bf16x8, pw);
      {
        bf16x8 vf = *reinterpret_cast<const bf16x8*>(vr + c * 1024);
        oacc0 = mfma32(vf, pf, oacc0);
      }
      {
        bf16x8 vf = *reinterpret_cast<const bf16x8*>(vr + 512 + c * 1024);
        oacc1 = mfma32(vf, pf, oacc1);
      }
    }
    __builtin_amdgcn_s_setprio(0);
    __syncthreads();
  }

  float l_;
  {
    float sv[8];
#pragma unroll
    for (int i = 0; i < 8; ++i) sv[i] = lacc[i] + lacc[i + 8];
#pragma unroll
    for (int s2 = 4; s2 >= 1; s2 >>= 1)
#pragma unroll
      for (int i = 0; i < s2; ++i) sv[i] += sv[i + s2];
    l_ = sv[0] + __shfl_xor(sv[0], 32);
  }

  {
    bf16_t* Os = &KVs[0][0] + w * 2048;
    const float inv = (NSPLIT == 1) ? __builtin_amdgcn_rcpf(l_) : 1.0f;
#pragma unroll
    for (int dh = 0; dh < 2; ++dh) {
      const f32x16 oa = dh ? oacc1 : oacc0;
#pragma unroll
      for (int g = 0; g < 8; ++g) {
        const int reg = g * 2;
        const int dl = (reg & 3) + 8 * (reg >> 2) + 4 * hi;
        const int d = dh * 32 + dl;
        const uint32_t wv = pk_bf16(oa[reg] * inv, oa[reg + 1] * inv);
        const int byte = lq * 128 + ((((d >> 3) ^ (lq & 7))) << 4) + ((d & 7) << 1);
        *reinterpret_cast<uint32_t*>(reinterpret_cast<char*>(Os) + byte) = wv;
      }
    }
    if (NSPLIT == 2 && lane < 32)
      Lp[(size_t)(z * 32 + bh) * 2048 + q0 + lq] = l_;
#pragma unroll
    for (int it = 0; it < 4; ++it) {
      const int q = it * 8 + (lane >> 3);
      const int ch = lane & 7;
      bf16x8 ov = *reinterpret_cast<const bf16x8*>(
          reinterpret_cast<char*>(Os) + q * 128 + ((ch ^ (q & 7)) << 4));
      if constexpr (NSPLIT == 1) {
        const size_t gaddr = (((size_t)(b * S_LEN + q0 + q)) << 10) + h * 64 + ch * 8;
        *reinterpret_cast<bf16x8*>(Og + gaddr) = ov;
      } else {
        const size_t rowoff = ((size_t)((z * 32 + bh) * 2048 + q0 + q)) << 6;
        *reinterpret_cast<bf16x8*>(Op + rowoff + ch * 8) = ov;
      }
    }
  }
#undef STAGE
}

// ---------------- combine two KV-half bf16 partials -> bf16 Ob ----------------
__global__ void attn_combine(const bf16_t* __restrict__ Op, const float* __restrict__ Lp,
                             bf16_t* __restrict__ Ob) {
  const int gid = blockIdx.x * 256 + threadIdx.x;   // 65536 rows x 8 chunks of 8
  const int row = gid >> 3, ch = gid & 7;
  const bf16_t* o1 = Op + ((size_t)row << 6) + ch * 8;
  const bf16_t* o2 = o1 + (1u << 22);               // + 65536*64 elems
  const float inv = 1.f / (Lp[row] + Lp[(1u << 16) + row]);
  bf16x8 v1 = *reinterpret_cast<const bf16x8*>(o1);
  bf16x8 v2 = *reinterpret_cast<const bf16x8*>(o2);
  bf16x8 o;
#pragma unroll
  for (int i = 0; i < 8; ++i) o[i] = (bf16_t)(((float)v1[i] + (float)v2[i]) * inv);
  const int bh = row >> 11, s = row & 2047;
  const int b = bh >> 4, h = bh & 15;
  *reinterpret_cast<bf16x8*>(Ob + (((size_t)(b * S_LEN + s)) << 10) + h * 64 + ch * 8) = o;
}

// ---------------------------------------------------------------------------
extern "C" void kernel_launch(void* const* d_in, const int* in_sizes, int n_in,
                              void* d_out, int out_size, void* d_ws, size_t ws_size,
                              hipStream_t stream) {
  const float* x = (const float*)d_in[0];
  const float* Wq = (const float*)d_in[1];
  const float* bq = (const float*)d_in[2];
  const float* Wk = (const float*)d_in[3];
  const float* bk = (const float*)d_in[4];
  const float* Wv = (const float*)d_in[5];
  const float* bv = (const float*)d_in[6];
  const float* Wo = (const float*)d_in[7];
  const float* bo = (const float*)d_in[8];
  const float* qnw = (const float*)d_in[9];
  const float* qnb = (const float*)d_in[10];
  const float* knw = (const float*)d_in[11];
  const float* knb = (const float*)d_in[12];
  float* out = (float*)d_out;

  uint8_t* ws = (uint8_t*)d_ws;
  bf16_t* xb = (bf16_t*)(ws + 0);          // [4096][1024]      8388608
  bf16_t* Wb = (bf16_t*)(ws + 8388608);    // [3072][1024]      6291456
  bf16_t* Wob = (bf16_t*)(ws + 14680064);  // [1024][1024]      2097152
  bf16_t* Qb = (bf16_t*)(ws + 16777216);   // [32][2048][64]    8388608
  bf16_t* Kb = (bf16_t*)(ws + 25165824);   // [32][2048][64]    8388608
  bf16_t* Vt = (bf16_t*)(ws + 33554432);   // [32][64][2048]    8388608
  bf16_t* Ob = (bf16_t*)(ws + 41943040);   // [4096][1024]      8388608
  bf16_t* Opart = (bf16_t*)(ws + 50331648);// [2][65536][64]bf16 16777216
  float*  Lpart = (float*)(ws + 67108864); // [2][65536]   f32     524288
  const bool split = ws_size >= 67633152ull;

  cvt_all<<<8192, 256, 0, stream>>>(x, Wq, Wk, Wv, Wo, xb, Wb, Wob);

  gemm_qkv_ln<<<192, 512, 0, stream>>>(xb, Wb, bq, bk, bv, qnw, qnb, knw, knb,
                                       Qb, Kb, Vt);
  if (split) {
    attn_kernel<2><<<dim3(16, 32, 2), 256, 0, stream>>>(Qb, Kb, Vt, Ob, Opart, Lpart);
    attn_combine<<<2048, 256, 0, stream>>>(Opart, Lpart, Ob);
  } else {
    attn_kernel<1><<<dim3(16, 32, 1), 256, 0, stream>>>(Qb, Kb, Vt, Ob, Opart, Lpart);
  }
  gemm_out<<<dim3(8, 64), 256, 0, stream>>>(Ob, Wob, bo, out);
}

// Round 11
// 120.749 us; speedup vs baseline: 1.0564x; 1.0564x over previous
//
#include <hip/hip_runtime.h>
#include <stdint.h>

// ---------------------------------------------------------------------------
// Fused MHA forward: B=2, S=2048, E=1024, H=16, D=64, fp32 in/out,
// bf16 MFMA compute internally. Exact (max-free) softmax: Q,K are LayerNorm'd
// so |score|*log2e <= ~23 -> exp2 never overflows; softmax is shift-invariant.
// qkv/gemm_out: R9 proven (128^2 / 64x128, BK=32, 2-phase; structural probes
// R6-R8,R10 all regressed). attn: tri-buffered KV + counted vmcnt(8) gate
// (T4: loads stay in flight across barriers; drain-to-0 removed).
// ---------------------------------------------------------------------------

typedef __bf16 bf16_t;
typedef __bf16 bf16x8 __attribute__((ext_vector_type(8)));
typedef __bf16 bf16x4 __attribute__((ext_vector_type(4)));
typedef __bf16 bf16x2 __attribute__((ext_vector_type(2)));
typedef float f32x4 __attribute__((ext_vector_type(4)));
typedef float f32x16 __attribute__((ext_vector_type(16)));
typedef uint32_t u32x4 __attribute__((ext_vector_type(4)));

#define S_LEN 2048
#define QSCALE 0.1803368801f   // 0.125 * log2(e), folded into Q at GEMM1

__device__ __forceinline__ void load_lds16(const void* g, void* l) {
  __builtin_amdgcn_global_load_lds((__attribute__((address_space(1))) void*)g,
                                   (__attribute__((address_space(3))) void*)l,
                                   16, 0, 0);
}

__device__ __forceinline__ f32x4 mfma16(bf16x8 a, bf16x8 b, f32x4 c) {
  return __builtin_amdgcn_mfma_f32_16x16x32_bf16(a, b, c, 0, 0, 0);
}

__device__ __forceinline__ f32x16 mfma32(bf16x8 a, bf16x8 b, f32x16 c) {
  return __builtin_amdgcn_mfma_f32_32x32x16_bf16(a, b, c, 0, 0, 0);
}

__device__ __forceinline__ uint32_t pk_bf16(float a, float b) {
  bf16x2 v; v[0] = (bf16_t)a; v[1] = (bf16_t)b;
  return __builtin_bit_cast(uint32_t, v);
}

__device__ __forceinline__ void plswap(uint32_t& a, uint32_t& b) {
  asm volatile("v_permlane32_swap_b32 %0, %1" : "+v"(a), "+v"(b));
}

// ---------------- fp32 -> bf16 convert, all tensors in one launch ----------
__global__ void cvt_all(const float* __restrict__ x, const float* __restrict__ Wq,
                        const float* __restrict__ Wk, const float* __restrict__ Wv,
                        const float* __restrict__ Wo,
                        bf16_t* __restrict__ xb, bf16_t* __restrict__ Wb,
                        bf16_t* __restrict__ Wob) {
  const int bid = blockIdx.x;
  const float* src; bf16_t* dst; int idx;
  if (bid < 4096) { src = x; dst = xb; idx = bid; }
  else {
    const int r = bid - 4096, rg = r >> 10;
    idx = r & 1023;
    if (rg == 0)      { src = Wq; dst = Wb; }
    else if (rg == 1) { src = Wk; dst = Wb + (1 << 20); }
    else if (rg == 2) { src = Wv; dst = Wb + (2 << 20); }
    else              { src = Wo; dst = Wob; }
  }
  const int i = (idx * 256 + threadIdx.x) * 4;
  float4 v = *reinterpret_cast<const float4*>(src + i);
  bf16x4 o;
  o[0] = (bf16_t)v.x; o[1] = (bf16_t)v.y; o[2] = (bf16_t)v.z; o[3] = (bf16_t)v.w;
  *reinterpret_cast<bf16x4*>(dst + i) = o;
}

// ---------------- GEMM1: QKV projection + bias + per-head LN ----------------
// 128x128 tile, BK=32, 2-phase dbuf. Q pre-scaled by QSCALE.
__launch_bounds__(256, 2)
__global__ void gemm_qkv_ln(const bf16_t* __restrict__ A, const bf16_t* __restrict__ Bt,
                            const float* __restrict__ bq, const float* __restrict__ bk,
                            const float* __restrict__ bv,
                            const float* __restrict__ qnw, const float* __restrict__ qnb,
                            const float* __restrict__ knw, const float* __restrict__ knb,
                            bf16_t* __restrict__ Qb, bf16_t* __restrict__ Kb,
                            bf16_t* __restrict__ Vt) {
  __shared__ alignas(16) bf16_t As[2][128 * 32];
  __shared__ alignas(16) bf16_t Bs[2][128 * 32];
  const int t = threadIdx.x;
  const int orig = blockIdx.y * 24 + blockIdx.x;          // 768 blocks
  const int logical = (orig & 7) * 96 + (orig >> 3);      // XCD-contiguous
  const int bn = logical % 24, bm = logical / 24;
  const int w = t >> 6, lane = t & 63;
  const int wr = w >> 1, wc = w & 1;
  const int lg = lane >> 4, lr = lane & 15;

  f32x4 acc[4][4] = {};
  const int srow = t >> 2;
  const int scol = (t & 3) << 3;
  const bf16_t* ga = A + ((size_t)(bm * 128 + srow) << 10) + scol;
  const bf16_t* gb = Bt + ((size_t)(bn * 128 + srow) << 10) + scol;

#define GSTAGE(buf, k0)                                        \
  {                                                            \
    load_lds16(ga + (k0),         &As[buf][t * 8]);            \
    load_lds16(ga + 65536 + (k0), &As[buf][2048 + t * 8]);     \
    load_lds16(gb + (k0),         &Bs[buf][t * 8]);            \
    load_lds16(gb + 65536 + (k0), &Bs[buf][2048 + t * 8]);     \
  }

  GSTAGE(0, 0);
  __syncthreads();
  for (int it = 0; it < 32; ++it) {
    const int cur = it & 1;
    if (it < 31) GSTAGE(cur ^ 1, (it + 1) << 5);
    bf16x8 af[4], bfr[4];
#pragma unroll
    for (int mt = 0; mt < 4; ++mt)
      af[mt] = *reinterpret_cast<const bf16x8*>(&As[cur][((wr * 64 + mt * 16 + lr) << 5) + lg * 8]);
#pragma unroll
    for (int nt = 0; nt < 4; ++nt)
      bfr[nt] = *reinterpret_cast<const bf16x8*>(&Bs[cur][((wc * 64 + nt * 16 + lr) << 5) + lg * 8]);
#pragma unroll
    for (int mt = 0; mt < 4; ++mt)
#pragma unroll
      for (int nt = 0; nt < 4; ++nt)
        acc[mt][nt] = mfma16(af[mt], bfr[nt], acc[mt][nt]);
    __syncthreads();
  }
#undef GSTAGE

  const int nbase = bn * 128 + wc * 64;
  const int region = nbase >> 10;         // 0=Q 1=K 2=V
  const int h = (nbase & 1023) >> 6;

  if (region == 2) {
    // --- V epilogue: per-wave 8KB LDS transpose -> coalesced 16B stores ---
    char* Vb = reinterpret_cast<char*>((w < 2) ? &As[w][0] : &Bs[w - 2][0]);
#pragma unroll
    for (int mt = 0; mt < 4; ++mt)
#pragma unroll
      for (int nt = 0; nt < 4; ++nt) {
        const int d = nt * 16 + lr;
        const float bvd = bv[h * 64 + d];
        const int slot = (mt * 2 + (lg >> 1)) ^ (d & 7);
        uint2 pr;
        pr.x = pk_bf16(acc[mt][nt][0] + bvd, acc[mt][nt][1] + bvd);
        pr.y = pk_bf16(acc[mt][nt][2] + bvd, acc[mt][nt][3] + bvd);
        *reinterpret_cast<uint2*>(Vb + d * 128 + slot * 16 + (lg & 1) * 8) = pr;
      }
    asm volatile("s_waitcnt lgkmcnt(0)" ::: "memory");
    const int s0 = bm * 128 + wr * 64;
    const int bb = s0 >> 11;
    const int sl = s0 & 2047;
#pragma unroll
    for (int it2 = 0; it2 < 8; ++it2) {
      const int d = it2 * 8 + (lane >> 3);
      const int ch = lane & 7;
      bf16x8 vv8 = *reinterpret_cast<const bf16x8*>(Vb + d * 128 + ((ch ^ (d & 7)) << 4));
      *reinterpret_cast<bf16x8*>(
          Vt + (((size_t)((bb * 16 + h) * 64 + d)) << 11) + sl + ch * 8) = vv8;
    }
  } else {
    const float* bias = region ? bk : bq;
    const float* lw = region ? knw : qnw;
    const float* lb = region ? knb : qnb;
    const float osc = region ? 1.0f : QSCALE;
    bf16_t* Outp = region ? Kb : Qb;
#pragma unroll
    for (int mt = 0; mt < 4; ++mt)
#pragma unroll
      for (int r = 0; r < 4; ++r) {
        const int gm = bm * 128 + wr * 64 + mt * 16 + lg * 4 + r;
        const int b = gm >> 11, s = gm & 2047;
        float vv[4], sum = 0.f, sumsq = 0.f;
#pragma unroll
        for (int nt = 0; nt < 4; ++nt) {
          const int d = nt * 16 + lr;
          vv[nt] = acc[mt][nt][r] + bias[h * 64 + d];
          sum += vv[nt];
          sumsq += vv[nt] * vv[nt];
        }
#pragma unroll
        for (int mk = 1; mk < 16; mk <<= 1) {
          sum += __shfl_xor(sum, mk);
          sumsq += __shfl_xor(sumsq, mk);
        }
        const float mean = sum * (1.f / 64.f);
        const float var = sumsq * (1.f / 64.f) - mean * mean;
        const float rstd = rsqrtf(var + 1e-5f);
        const size_t rowoff = ((size_t)((b * 16 + h) * 2048 + s)) << 6;
#pragma unroll
        for (int nt = 0; nt < 4; ++nt) {
          const int d = nt * 16 + lr;
          float y = ((vv[nt] - mean) * rstd * lw[d] + lb[d]) * osc;
          Outp[rowoff + d] = (bf16_t)y;
        }
      }
  }
}

// ---------------- GEMM2: output projection, 64x128 tile, 2-phase dbuf -------
__launch_bounds__(256, 2)
__global__ void gemm_out(const bf16_t* __restrict__ A, const bf16_t* __restrict__ Bt,
                         const float* __restrict__ bo, float* __restrict__ dout) {
  __shared__ alignas(16) bf16_t As[2][64 * 32];
  __shared__ alignas(16) bf16_t Bs[2][128 * 32];
  const int t = threadIdx.x;
  const int orig = blockIdx.y * 8 + blockIdx.x;           // 512 blocks
  const int logical = (orig & 7) * 64 + (orig >> 3);
  const int bn = logical & 7, bm = logical >> 3;
  const int w = t >> 6, lane = t & 63;
  const int wr = w >> 1, wc = w & 1;                      // wave tile 32x64
  const int lg = lane >> 4, lr = lane & 15;

  f32x4 acc[2][4] = {};
  const int srow = t >> 2;
  const int scol = (t & 3) << 3;
  const bf16_t* ga = A + ((size_t)(bm * 64 + srow) << 10) + scol;
  const bf16_t* gb = Bt + ((size_t)(bn * 128 + srow) << 10) + scol;

#define OSTAGE(buf, k0)                                        \
  {                                                            \
    load_lds16(ga + (k0),         &As[buf][t * 8]);            \
    load_lds16(gb + (k0),         &Bs[buf][t * 8]);            \
    load_lds16(gb + 65536 + (k0), &Bs[buf][2048 + t * 8]);     \
  }

  OSTAGE(0, 0);
  __syncthreads();
  for (int it = 0; it < 32; ++it) {
    const int cur = it & 1;
    if (it < 31) OSTAGE(cur ^ 1, (it + 1) << 5);
    bf16x8 af[2], bfr[4];
#pragma unroll
    for (int mt = 0; mt < 2; ++mt)
      af[mt] = *reinterpret_cast<const bf16x8*>(&As[cur][((wr * 32 + mt * 16 + lr) << 5) + lg * 8]);
#pragma unroll
    for (int nt = 0; nt < 4; ++nt)
      bfr[nt] = *reinterpret_cast<const bf16x8*>(&Bs[cur][((wc * 64 + nt * 16 + lr) << 5) + lg * 8]);
#pragma unroll
    for (int mt = 0; mt < 2; ++mt)
#pragma unroll
      for (int nt = 0; nt < 4; ++nt)
        acc[mt][nt] = mfma16(af[mt], bfr[nt], acc[mt][nt]);
    __syncthreads();
  }
#undef OSTAGE

#pragma unroll
  for (int mt = 0; mt < 2; ++mt)
#pragma unroll
    for (int r = 0; r < 4; ++r) {
      const int gm = bm * 64 + wr * 32 + mt * 16 + lg * 4 + r;
#pragma unroll
      for (int nt = 0; nt < 4; ++nt) {
        const int gn = bn * 128 + wc * 64 + nt * 16 + lr;
        dout[((size_t)gm << 10) + gn] = acc[mt][nt][r] + bo[gn];
      }
    }
}

// ---------------- flash attention, max-free softmax, tri-buffered KV --------
// Block: 4 waves x 32 q = 128 q. Grid (16, 32, NSPLIT), XCD-swizzled.
// KV slots: K in KVs[0..2], V in KVs[3..5] (8KB each, conflict-free layout
// elem(row,ch8) = (ch8>>1)*1024 + row*16 + (ch8&1)*8; source-permuted stage).
// Pipeline: stage tile j+2 at top of iter j; gate s_waitcnt vmcnt(8) (tiles
// j+1,j+2 stay in flight -- never drained to 0); clamped staging at the tail
// keeps the vmcnt ledger uniform. 2 raw barriers/iter, no vmcnt(0) drain.
template <int NSPLIT>
__launch_bounds__(256, 3)
__global__ void attn_kernel(const bf16_t* __restrict__ Qb, const bf16_t* __restrict__ Kb,
                            const bf16_t* __restrict__ Vt, bf16_t* __restrict__ Og,
                            bf16_t* __restrict__ Op, float* __restrict__ Lp) {
  __shared__ alignas(16) bf16_t KVs[6][64 * 64];  // 48 KB

  const int t = threadIdx.x;
  const int w = t >> 6, lane = t & 63;
  const int lq = lane & 31;
  const int hi = lane >> 5;
  const int orig = (blockIdx.z * 32 + blockIdx.y) * 16 + blockIdx.x;
  const int logical = (orig & 7) * (64 * NSPLIT) + (orig >> 3);  // XCD-contig
  const int qt = logical & 15;
  const int bh = (logical >> 4) & 31;
  const int z = (NSPLIT == 1) ? 0 : (logical >> 9);
  const int b = bh >> 4, h = bh & 15;
  const int q0 = qt * 128 + w * 32;
  const int ntiles = 32 / NSPLIT;

  bf16x8 qf[4];   // Q pre-scaled by QSCALE in GEMM1
  {
    const bf16_t* qp = Qb + (((size_t)bh * S_LEN + q0 + lq) << 6) + hi * 8;
#pragma unroll
    for (int c = 0; c < 4; ++c)
      qf[c] = *reinterpret_cast<const bf16x8*>(qp + c * 16);
  }

  f32x16 oacc0 = {}, oacc1 = {}, lacc = {};

  const int krow = (t >> 1) & 63;
  const int kch = ((t >> 7) << 1) | (t & 1);
  const bf16_t* kbase = Kb + (((size_t)bh * S_LEN) << 6) + krow * 64 + kch * 8;
  const bf16_t* vbase = Vt + ((size_t)bh << 17) + krow * S_LEN + kch * 8;

#define STAGE(slot, jt)                                                      \
  {                                                                          \
    const bf16_t* kb_ = kbase + (((size_t)(jt)) << 12);                      \
    const bf16_t* vb_ = vbase + (jt) * 64;                                   \
    load_lds16(kb_,      &KVs[slot][t * 8]);                                 \
    load_lds16(kb_ + 32, &KVs[slot][2048 + t * 8]);                          \
    load_lds16(vb_,      &KVs[3 + (slot)][t * 8]);                           \
    load_lds16(vb_ + 32, &KVs[3 + (slot)][2048 + t * 8]);                    \
  }

  STAGE(0, z * ntiles);
  STAGE(1, z * ntiles + 1);

  int sl = 0, sl2 = 2;
  for (int j = 0; j < ntiles; ++j) {
    const int jc = (j + 2 < ntiles) ? (j + 2) : (ntiles - 1);  // clamp: uniform counts
    STAGE(sl2, z * ntiles + jc);
    asm volatile("s_waitcnt vmcnt(8)" ::: "memory");   // tile j landed; j+1,j+2 in flight
    __builtin_amdgcn_sched_barrier(0);
    __builtin_amdgcn_s_barrier();
    __builtin_amdgcn_sched_barrier(0);

    f32x16 s0 = {}, s1 = {};
    const bf16_t* kr = &KVs[sl][lq * 16 + hi * 8];
    __builtin_amdgcn_s_setprio(1);
#pragma unroll
    for (int c = 0; c < 4; ++c) {
      bf16x8 kf = *reinterpret_cast<const bf16x8*>(kr + c * 1024);
      s0 = mfma32(kf, qf[c], s0);
    }
#pragma unroll
    for (int c = 0; c < 4; ++c) {
      bf16x8 kf = *reinterpret_cast<const bf16x8*>(kr + 512 + c * 1024);
      s1 = mfma32(kf, qf[c], s1);
    }
    __builtin_amdgcn_s_setprio(0);

    f32x16 p0, p1;
#pragma unroll
    for (int i = 0; i < 16; ++i) p0[i] = __builtin_amdgcn_exp2f(s0[i]);
#pragma unroll
    for (int i = 0; i < 16; ++i) p1[i] = __builtin_amdgcn_exp2f(s1[i]);
    lacc += p0;
    lacc += p1;

    const bf16_t* vr = &KVs[3 + sl][lq * 16 + hi * 8];
    __builtin_amdgcn_s_setprio(1);
#pragma unroll
    for (int c = 0; c < 4; ++c) {
      const f32x16 ph = (c < 2) ? p0 : p1;
      const int cl = c & 1;
      uint32_t w00 = pk_bf16(ph[8 * cl + 0], ph[8 * cl + 1]);
      uint32_t w01 = pk_bf16(ph[8 * cl + 2], ph[8 * cl + 3]);
      uint32_t w10 = pk_bf16(ph[8 * cl + 4], ph[8 * cl + 5]);
      uint32_t w11 = pk_bf16(ph[8 * cl + 6], ph[8 * cl + 7]);
      plswap(w00, w10);
      plswap(w01, w11);
      u32x4 pw = {w00, w01, w10, w11};
      bf16x8 pf = __builtin_bit_cast(bf16x8, pw);
      {
        bf16x8 vf = *reinterpret_cast<const bf16x8*>(vr + c * 1024);
        oacc0 = mfma32(vf, pf, oacc0);
      }
      {
        bf16x8 vf = *reinterpret_cast<const bf16x8*>(vr + 512 + c * 1024);
        oacc1 = mfma32(vf, pf, oacc1);
      }
    }
    __builtin_amdgcn_s_setprio(0);
    __builtin_amdgcn_s_barrier();   // protect slot about to be overwritten
    sl = (sl == 2) ? 0 : sl + 1;
    sl2 = (sl2 == 2) ? 0 : sl2 + 1;
  }

  float l_;
  {
    float sv[8];
#pragma unroll
    for (int i = 0; i < 8; ++i) sv[i] = lacc[i] + lacc[i + 8];
#pragma unroll
    for (int s2 = 4; s2 >= 1; s2 >>= 1)
#pragma unroll
      for (int i = 0; i < s2; ++i) sv[i] += sv[i + s2];
    l_ = sv[0] + __shfl_xor(sv[0], 32);
  }

  {
    bf16_t* Os = &KVs[0][0] + w * 2048;
    const float inv = (NSPLIT == 1) ? __builtin_amdgcn_rcpf(l_) : 1.0f;
#pragma unroll
    for (int dh = 0; dh < 2; ++dh) {
      const f32x16 oa = dh ? oacc1 : oacc0;
#pragma unroll
      for (int g = 0; g < 8; ++g) {
        const int reg = g * 2;
        const int dl = (reg & 3) + 8 * (reg >> 2) + 4 * hi;
        const int d = dh * 32 + dl;
        const uint32_t wv = pk_bf16(oa[reg] * inv, oa[reg + 1] * inv);
        const int byte = lq * 128 + ((((d >> 3) ^ (lq & 7))) << 4) + ((d & 7) << 1);
        *reinterpret_cast<uint32_t*>(reinterpret_cast<char*>(Os) + byte) = wv;
      }
    }
    if (NSPLIT == 2 && lane < 32)
      Lp[(size_t)(z * 32 + bh) * 2048 + q0 + lq] = l_;
#pragma unroll
    for (int it = 0; it < 4; ++it) {
      const int q = it * 8 + (lane >> 3);
      const int ch = lane & 7;
      bf16x8 ov = *reinterpret_cast<const bf16x8*>(
          reinterpret_cast<char*>(Os) + q * 128 + ((ch ^ (q & 7)) << 4));
      if constexpr (NSPLIT == 1) {
        const size_t gaddr = (((size_t)(b * S_LEN + q0 + q)) << 10) + h * 64 + ch * 8;
        *reinterpret_cast<bf16x8*>(Og + gaddr) = ov;
      } else {
        const size_t rowoff = ((size_t)((z * 32 + bh) * 2048 + q0 + q)) << 6;
        *reinterpret_cast<bf16x8*>(Op + rowoff + ch * 8) = ov;
      }
    }
  }
#undef STAGE
}

// ---------------- combine two KV-half bf16 partials -> bf16 Ob ----------------
__global__ void attn_combine(const bf16_t* __restrict__ Op, const float* __restrict__ Lp,
                             bf16_t* __restrict__ Ob) {
  const int gid = blockIdx.x * 256 + threadIdx.x;   // 65536 rows x 8 chunks of 8
  const int row = gid >> 3, ch = gid & 7;
  const bf16_t* o1 = Op + ((size_t)row << 6) + ch * 8;
  const bf16_t* o2 = o1 + (1u << 22);               // + 65536*64 elems
  const float inv = 1.f / (Lp[row] + Lp[(1u << 16) + row]);
  bf16x8 v1 = *reinterpret_cast<const bf16x8*>(o1);
  bf16x8 v2 = *reinterpret_cast<const bf16x8*>(o2);
  bf16x8 o;
#pragma unroll
  for (int i = 0; i < 8; ++i) o[i] = (bf16_t)(((float)v1[i] + (float)v2[i]) * inv);
  const int bh = row >> 11, s = row & 2047;
  const int b = bh >> 4, h = bh & 15;
  *reinterpret_cast<bf16x8*>(Ob + (((size_t)(b * S_LEN + s)) << 10) + h * 64 + ch * 8) = o;
}

// ---------------------------------------------------------------------------
extern "C" void kernel_launch(void* const* d_in, const int* in_sizes, int n_in,
                              void* d_out, int out_size, void* d_ws, size_t ws_size,
                              hipStream_t stream) {
  const float* x = (const float*)d_in[0];
  const float* Wq = (const float*)d_in[1];
  const float* bq = (const float*)d_in[2];
  const float* Wk = (const float*)d_in[3];
  const float* bk = (const float*)d_in[4];
  const float* Wv = (const float*)d_in[5];
  const float* bv = (const float*)d_in[6];
  const float* Wo = (const float*)d_in[7];
  const float* bo = (const float*)d_in[8];
  const float* qnw = (const float*)d_in[9];
  const float* qnb = (const float*)d_in[10];
  const float* knw = (const float*)d_in[11];
  const float* knb = (const float*)d_in[12];
  float* out = (float*)d_out;

  uint8_t* ws = (uint8_t*)d_ws;
  bf16_t* xb = (bf16_t*)(ws + 0);          // [4096][1024]      8388608
  bf16_t* Wb = (bf16_t*)(ws + 8388608);    // [3072][1024]      6291456
  bf16_t* Wob = (bf16_t*)(ws + 14680064);  // [1024][1024]      2097152
  bf16_t* Qb = (bf16_t*)(ws + 16777216);   // [32][2048][64]    8388608
  bf16_t* Kb = (bf16_t*)(ws + 25165824);   // [32][2048][64]    8388608
  bf16_t* Vt = (bf16_t*)(ws + 33554432);   // [32][64][2048]    8388608
  bf16_t* Ob = (bf16_t*)(ws + 41943040);   // [4096][1024]      8388608
  bf16_t* Opart = (bf16_t*)(ws + 50331648);// [2][65536][64]bf16 16777216
  float*  Lpart = (float*)(ws + 67108864); // [2][65536]   f32     524288
  const bool split = ws_size >= 67633152ull;

  cvt_all<<<8192, 256, 0, stream>>>(x, Wq, Wk, Wv, Wo, xb, Wb, Wob);

  gemm_qkv_ln<<<dim3(24, 32), 256, 0, stream>>>(xb, Wb, bq, bk, bv, qnw, qnb, knw, knb,
                                                Qb, Kb, Vt);
  if (split) {
    attn_kernel<2><<<dim3(16, 32, 2), 256, 0, stream>>>(Qb, Kb, Vt, Ob, Opart, Lpart);
    attn_combine<<<2048, 256, 0, stream>>>(Opart, Lpart, Ob);
  } else {
    attn_kernel<1><<<dim3(16, 32, 1), 256, 0, stream>>>(Qb, Kb, Vt, Ob, Opart, Lpart);
  }
  gemm_out<<<dim3(8, 64), 256, 0, stream>>>(Ob, Wob, bo, out);
}

// Round 12
// 117.234 us; speedup vs baseline: 1.0881x; 1.0300x over previous
//
#include <hip/hip_runtime.h>
#include <stdint.h>

// ---------------------------------------------------------------------------
// Fused MHA forward: B=2, S=2048, E=1024, H=16, D=64, fp32 in/out,
// bf16 MFMA compute internally. Exact (max-free) softmax: Q,K are LayerNorm'd
// so |score|*log2e <= ~23 -> exp2 never overflows; softmax is shift-invariant.
// R9 configuration == measured optimum (117.3us). Structural probes that
// REGRESSED (do not retry): 64-col tiles (R6), BK=64 (R7), combine-fusion
// into gemm_out (R8), 256^2 8-phase qkv (R10, grid 192<256 CUs), tri-buffered
// counted-vmcnt attn (R11, occupancy 4->3 blocks/CU).
// ---------------------------------------------------------------------------

typedef __bf16 bf16_t;
typedef __bf16 bf16x8 __attribute__((ext_vector_type(8)));
typedef __bf16 bf16x4 __attribute__((ext_vector_type(4)));
typedef __bf16 bf16x2 __attribute__((ext_vector_type(2)));
typedef float f32x4 __attribute__((ext_vector_type(4)));
typedef float f32x16 __attribute__((ext_vector_type(16)));
typedef uint32_t u32x4 __attribute__((ext_vector_type(4)));

#define S_LEN 2048
#define QSCALE 0.1803368801f   // 0.125 * log2(e), folded into Q at GEMM1

__device__ __forceinline__ void load_lds16(const void* g, void* l) {
  __builtin_amdgcn_global_load_lds((__attribute__((address_space(1))) void*)g,
                                   (__attribute__((address_space(3))) void*)l,
                                   16, 0, 0);
}

__device__ __forceinline__ f32x4 mfma16(bf16x8 a, bf16x8 b, f32x4 c) {
  return __builtin_amdgcn_mfma_f32_16x16x32_bf16(a, b, c, 0, 0, 0);
}

__device__ __forceinline__ f32x16 mfma32(bf16x8 a, bf16x8 b, f32x16 c) {
  return __builtin_amdgcn_mfma_f32_32x32x16_bf16(a, b, c, 0, 0, 0);
}

__device__ __forceinline__ uint32_t pk_bf16(float a, float b) {
  bf16x2 v; v[0] = (bf16_t)a; v[1] = (bf16_t)b;
  return __builtin_bit_cast(uint32_t, v);
}

__device__ __forceinline__ void plswap(uint32_t& a, uint32_t& b) {
  asm volatile("v_permlane32_swap_b32 %0, %1" : "+v"(a), "+v"(b));
}

// ---------------- fp32 -> bf16 convert, all tensors in one launch ----------
__global__ void cvt_all(const float* __restrict__ x, const float* __restrict__ Wq,
                        const float* __restrict__ Wk, const float* __restrict__ Wv,
                        const float* __restrict__ Wo,
                        bf16_t* __restrict__ xb, bf16_t* __restrict__ Wb,
                        bf16_t* __restrict__ Wob) {
  const int bid = blockIdx.x;
  const float* src; bf16_t* dst; int idx;
  if (bid < 4096) { src = x; dst = xb; idx = bid; }
  else {
    const int r = bid - 4096, rg = r >> 10;
    idx = r & 1023;
    if (rg == 0)      { src = Wq; dst = Wb; }
    else if (rg == 1) { src = Wk; dst = Wb + (1 << 20); }
    else if (rg == 2) { src = Wv; dst = Wb + (2 << 20); }
    else              { src = Wo; dst = Wob; }
  }
  const int i = (idx * 256 + threadIdx.x) * 4;
  float4 v = *reinterpret_cast<const float4*>(src + i);
  bf16x4 o;
  o[0] = (bf16_t)v.x; o[1] = (bf16_t)v.y; o[2] = (bf16_t)v.z; o[3] = (bf16_t)v.w;
  *reinterpret_cast<bf16x4*>(dst + i) = o;
}

// ---------------- GEMM1: QKV projection + bias + per-head LN ----------------
// 128x128 tile, BK=32, 2-phase dbuf. Q pre-scaled by QSCALE.
__launch_bounds__(256, 2)
__global__ void gemm_qkv_ln(const bf16_t* __restrict__ A, const bf16_t* __restrict__ Bt,
                            const float* __restrict__ bq, const float* __restrict__ bk,
                            const float* __restrict__ bv,
                            const float* __restrict__ qnw, const float* __restrict__ qnb,
                            const float* __restrict__ knw, const float* __restrict__ knb,
                            bf16_t* __restrict__ Qb, bf16_t* __restrict__ Kb,
                            bf16_t* __restrict__ Vt) {
  __shared__ alignas(16) bf16_t As[2][128 * 32];
  __shared__ alignas(16) bf16_t Bs[2][128 * 32];
  const int t = threadIdx.x;
  const int orig = blockIdx.y * 24 + blockIdx.x;          // 768 blocks
  const int logical = (orig & 7) * 96 + (orig >> 3);      // XCD-contiguous
  const int bn = logical % 24, bm = logical / 24;
  const int w = t >> 6, lane = t & 63;
  const int wr = w >> 1, wc = w & 1;
  const int lg = lane >> 4, lr = lane & 15;

  f32x4 acc[4][4] = {};
  const int srow = t >> 2;
  const int scol = (t & 3) << 3;
  const bf16_t* ga = A + ((size_t)(bm * 128 + srow) << 10) + scol;
  const bf16_t* gb = Bt + ((size_t)(bn * 128 + srow) << 10) + scol;

#define GSTAGE(buf, k0)                                        \
  {                                                            \
    load_lds16(ga + (k0),         &As[buf][t * 8]);            \
    load_lds16(ga + 65536 + (k0), &As[buf][2048 + t * 8]);     \
    load_lds16(gb + (k0),         &Bs[buf][t * 8]);            \
    load_lds16(gb + 65536 + (k0), &Bs[buf][2048 + t * 8]);     \
  }

  GSTAGE(0, 0);
  __syncthreads();
  for (int it = 0; it < 32; ++it) {
    const int cur = it & 1;
    if (it < 31) GSTAGE(cur ^ 1, (it + 1) << 5);
    bf16x8 af[4], bfr[4];
#pragma unroll
    for (int mt = 0; mt < 4; ++mt)
      af[mt] = *reinterpret_cast<const bf16x8*>(&As[cur][((wr * 64 + mt * 16 + lr) << 5) + lg * 8]);
#pragma unroll
    for (int nt = 0; nt < 4; ++nt)
      bfr[nt] = *reinterpret_cast<const bf16x8*>(&Bs[cur][((wc * 64 + nt * 16 + lr) << 5) + lg * 8]);
#pragma unroll
    for (int mt = 0; mt < 4; ++mt)
#pragma unroll
      for (int nt = 0; nt < 4; ++nt)
        acc[mt][nt] = mfma16(af[mt], bfr[nt], acc[mt][nt]);
    __syncthreads();
  }
#undef GSTAGE

  const int nbase = bn * 128 + wc * 64;
  const int region = nbase >> 10;         // 0=Q 1=K 2=V
  const int h = (nbase & 1023) >> 6;

  if (region == 2) {
    // --- V epilogue: per-wave 8KB LDS transpose -> coalesced 16B stores ---
    char* Vb = reinterpret_cast<char*>((w < 2) ? &As[w][0] : &Bs[w - 2][0]);
#pragma unroll
    for (int mt = 0; mt < 4; ++mt)
#pragma unroll
      for (int nt = 0; nt < 4; ++nt) {
        const int d = nt * 16 + lr;
        const float bvd = bv[h * 64 + d];
        const int slot = (mt * 2 + (lg >> 1)) ^ (d & 7);
        uint2 pr;
        pr.x = pk_bf16(acc[mt][nt][0] + bvd, acc[mt][nt][1] + bvd);
        pr.y = pk_bf16(acc[mt][nt][2] + bvd, acc[mt][nt][3] + bvd);
        *reinterpret_cast<uint2*>(Vb + d * 128 + slot * 16 + (lg & 1) * 8) = pr;
      }
    asm volatile("s_waitcnt lgkmcnt(0)" ::: "memory");
    const int s0 = bm * 128 + wr * 64;
    const int bb = s0 >> 11;
    const int sl = s0 & 2047;
#pragma unroll
    for (int it2 = 0; it2 < 8; ++it2) {
      const int d = it2 * 8 + (lane >> 3);
      const int ch = lane & 7;
      bf16x8 vv8 = *reinterpret_cast<const bf16x8*>(Vb + d * 128 + ((ch ^ (d & 7)) << 4));
      *reinterpret_cast<bf16x8*>(
          Vt + (((size_t)((bb * 16 + h) * 64 + d)) << 11) + sl + ch * 8) = vv8;
    }
  } else {
    const float* bias = region ? bk : bq;
    const float* lw = region ? knw : qnw;
    const float* lb = region ? knb : qnb;
    const float osc = region ? 1.0f : QSCALE;
    bf16_t* Outp = region ? Kb : Qb;
#pragma unroll
    for (int mt = 0; mt < 4; ++mt)
#pragma unroll
      for (int r = 0; r < 4; ++r) {
        const int gm = bm * 128 + wr * 64 + mt * 16 + lg * 4 + r;
        const int b = gm >> 11, s = gm & 2047;
        float vv[4], sum = 0.f, sumsq = 0.f;
#pragma unroll
        for (int nt = 0; nt < 4; ++nt) {
          const int d = nt * 16 + lr;
          vv[nt] = acc[mt][nt][r] + bias[h * 64 + d];
          sum += vv[nt];
          sumsq += vv[nt] * vv[nt];
        }
#pragma unroll
        for (int mk = 1; mk < 16; mk <<= 1) {
          sum += __shfl_xor(sum, mk);
          sumsq += __shfl_xor(sumsq, mk);
        }
        const float mean = sum * (1.f / 64.f);
        const float var = sumsq * (1.f / 64.f) - mean * mean;
        const float rstd = rsqrtf(var + 1e-5f);
        const size_t rowoff = ((size_t)((b * 16 + h) * 2048 + s)) << 6;
#pragma unroll
        for (int nt = 0; nt < 4; ++nt) {
          const int d = nt * 16 + lr;
          float y = ((vv[nt] - mean) * rstd * lw[d] + lb[d]) * osc;
          Outp[rowoff + d] = (bf16_t)y;
        }
      }
  }
}

// ---------------- GEMM2: output projection, 64x128 tile, 2-phase dbuf -------
__launch_bounds__(256, 2)
__global__ void gemm_out(const bf16_t* __restrict__ A, const bf16_t* __restrict__ Bt,
                         const float* __restrict__ bo, float* __restrict__ dout) {
  __shared__ alignas(16) bf16_t As[2][64 * 32];
  __shared__ alignas(16) bf16_t Bs[2][128 * 32];
  const int t = threadIdx.x;
  const int orig = blockIdx.y * 8 + blockIdx.x;           // 512 blocks
  const int logical = (orig & 7) * 64 + (orig >> 3);
  const int bn = logical & 7, bm = logical >> 3;
  const int w = t >> 6, lane = t & 63;
  const int wr = w >> 1, wc = w & 1;                      // wave tile 32x64
  const int lg = lane >> 4, lr = lane & 15;

  f32x4 acc[2][4] = {};
  const int srow = t >> 2;
  const int scol = (t & 3) << 3;
  const bf16_t* ga = A + ((size_t)(bm * 64 + srow) << 10) + scol;
  const bf16_t* gb = Bt + ((size_t)(bn * 128 + srow) << 10) + scol;

#define OSTAGE(buf, k0)                                        \
  {                                                            \
    load_lds16(ga + (k0),         &As[buf][t * 8]);            \
    load_lds16(gb + (k0),         &Bs[buf][t * 8]);            \
    load_lds16(gb + 65536 + (k0), &Bs[buf][2048 + t * 8]);     \
  }

  OSTAGE(0, 0);
  __syncthreads();
  for (int it = 0; it < 32; ++it) {
    const int cur = it & 1;
    if (it < 31) OSTAGE(cur ^ 1, (it + 1) << 5);
    bf16x8 af[2], bfr[4];
#pragma unroll
    for (int mt = 0; mt < 2; ++mt)
      af[mt] = *reinterpret_cast<const bf16x8*>(&As[cur][((wr * 32 + mt * 16 + lr) << 5) + lg * 8]);
#pragma unroll
    for (int nt = 0; nt < 4; ++nt)
      bfr[nt] = *reinterpret_cast<const bf16x8*>(&Bs[cur][((wc * 64 + nt * 16 + lr) << 5) + lg * 8]);
#pragma unroll
    for (int mt = 0; mt < 2; ++mt)
#pragma unroll
      for (int nt = 0; nt < 4; ++nt)
        acc[mt][nt] = mfma16(af[mt], bfr[nt], acc[mt][nt]);
    __syncthreads();
  }
#undef OSTAGE

#pragma unroll
  for (int mt = 0; mt < 2; ++mt)
#pragma unroll
    for (int r = 0; r < 4; ++r) {
      const int gm = bm * 64 + wr * 32 + mt * 16 + lg * 4 + r;
#pragma unroll
      for (int nt = 0; nt < 4; ++nt) {
        const int gn = bn * 128 + wc * 64 + nt * 16 + lr;
        dout[((size_t)gm << 10) + gn] = acc[mt][nt][r] + bo[gn];
      }
    }
}

// ---------------- flash attention, max-free softmax ----------
// Block: 4 waves x 32 q = 128 q. Grid (16, 32, NSPLIT), XCD-swizzled.
// LDS tile layout (8KB, conflict-free): elem(row, ch8) =
//   (ch8>>1)*1024 + row*16 + (ch8&1)*8. Staged via global_load_lds with the
// permutation applied on the global source (linear LDS dest).
// NSPLIT=2: bf16 unnormalized partials + fp32 l.
template <int NSPLIT>
__launch_bounds__(256, 4)
__global__ void attn_kernel(const bf16_t* __restrict__ Qb, const bf16_t* __restrict__ Kb,
                            const bf16_t* __restrict__ Vt, bf16_t* __restrict__ Og,
                            bf16_t* __restrict__ Op, float* __restrict__ Lp) {
  __shared__ alignas(16) bf16_t KVs[4][64 * 64];  // [0..1]=K dbuf, [2..3]=V dbuf

  const int t = threadIdx.x;
  const int w = t >> 6, lane = t & 63;
  const int lq = lane & 31;
  const int hi = lane >> 5;
  const int orig = (blockIdx.z * 32 + blockIdx.y) * 16 + blockIdx.x;
  const int logical = (orig & 7) * (64 * NSPLIT) + (orig >> 3);  // XCD-contig
  const int qt = logical & 15;
  const int bh = (logical >> 4) & 31;
  const int z = (NSPLIT == 1) ? 0 : (logical >> 9);
  const int b = bh >> 4, h = bh & 15;
  const int q0 = qt * 128 + w * 32;
  const int ntiles = 32 / NSPLIT;

  bf16x8 qf[4];   // Q pre-scaled by QSCALE in GEMM1
  {
    const bf16_t* qp = Qb + (((size_t)bh * S_LEN + q0 + lq) << 6) + hi * 8;
#pragma unroll
    for (int c = 0; c < 4; ++c)
      qf[c] = *reinterpret_cast<const bf16x8*>(qp + c * 16);
  }

  f32x16 oacc0 = {}, oacc1 = {}, lacc = {};

  const int krow = (t >> 1) & 63;
  const int kch = ((t >> 7) << 1) | (t & 1);
  const bf16_t* kbase = Kb + (((size_t)bh * S_LEN) << 6) + krow * 64 + kch * 8;
  const bf16_t* vbase = Vt + ((size_t)bh << 17) + krow * S_LEN + kch * 8;

#define STAGE(buf, jt)                                                       \
  {                                                                          \
    const bf16_t* kb_ = kbase + (((size_t)(jt)) << 12);                      \
    const bf16_t* vb_ = vbase + (jt) * 64;                                   \
    load_lds16(kb_,      &KVs[buf][t * 8]);                                  \
    load_lds16(kb_ + 32, &KVs[buf][2048 + t * 8]);                           \
    load_lds16(vb_,      &KVs[2 + (buf)][t * 8]);                            \
    load_lds16(vb_ + 32, &KVs[2 + (buf)][2048 + t * 8]);                     \
  }

  STAGE(0, z * ntiles);
  __syncthreads();

  for (int j = 0; j < ntiles; ++j) {
    const int cur = j & 1;
    if (j < ntiles - 1) STAGE(cur ^ 1, z * ntiles + j + 1);

    f32x16 s0 = {}, s1 = {};
    const bf16_t* kr = &KVs[cur][lq * 16 + hi * 8];
    __builtin_amdgcn_s_setprio(1);
#pragma unroll
    for (int c = 0; c < 4; ++c) {
      bf16x8 kf = *reinterpret_cast<const bf16x8*>(kr + c * 1024);
      s0 = mfma32(kf, qf[c], s0);
    }
#pragma unroll
    for (int c = 0; c < 4; ++c) {
      bf16x8 kf = *reinterpret_cast<const bf16x8*>(kr + 512 + c * 1024);
      s1 = mfma32(kf, qf[c], s1);
    }
    __builtin_amdgcn_s_setprio(0);

    f32x16 p0, p1;
#pragma unroll
    for (int i = 0; i < 16; ++i) p0[i] = __builtin_amdgcn_exp2f(s0[i]);
#pragma unroll
    for (int i = 0; i < 16; ++i) p1[i] = __builtin_amdgcn_exp2f(s1[i]);
    lacc += p0;
    lacc += p1;

    const bf16_t* vr = &KVs[2 + cur][lq * 16 + hi * 8];
    __builtin_amdgcn_s_setprio(1);
#pragma unroll
    for (int c = 0; c < 4; ++c) {
      const f32x16 ph = (c < 2) ? p0 : p1;
      const int cl = c & 1;
      uint32_t w00 = pk_bf16(ph[8 * cl + 0], ph[8 * cl + 1]);
      uint32_t w01 = pk_bf16(ph[8 * cl + 2], ph[8 * cl + 3]);
      uint32_t w10 = pk_bf16(ph[8 * cl + 4], ph[8 * cl + 5]);
      uint32_t w11 = pk_bf16(ph[8 * cl + 6], ph[8 * cl + 7]);
      plswap(w00, w10);
      plswap(w01, w11);
      u32x4 pw = {w00, w01, w10, w11};
      bf16x8 pf = __builtin_bit_cast(bf16x8, pw);
      {
        bf16x8 vf = *reinterpret_cast<const bf16x8*>(vr + c * 1024);
        oacc0 = mfma32(vf, pf, oacc0);
      }
      {
        bf16x8 vf = *reinterpret_cast<const bf16x8*>(vr + 512 + c * 1024);
        oacc1 = mfma32(vf, pf, oacc1);
      }
    }
    __builtin_amdgcn_s_setprio(0);
    __syncthreads();
  }

  float l_;
  {
    float sv[8];
#pragma unroll
    for (int i = 0; i < 8; ++i) sv[i] = lacc[i] + lacc[i + 8];
#pragma unroll
    for (int s2 = 4; s2 >= 1; s2 >>= 1)
#pragma unroll
      for (int i = 0; i < s2; ++i) sv[i] += sv[i + s2];
    l_ = sv[0] + __shfl_xor(sv[0], 32);
  }

  {
    bf16_t* Os = &KVs[0][0] + w * 2048;
    const float inv = (NSPLIT == 1) ? __builtin_amdgcn_rcpf(l_) : 1.0f;
#pragma unroll
    for (int dh = 0; dh < 2; ++dh) {
      const f32x16 oa = dh ? oacc1 : oacc0;
#pragma unroll
      for (int g = 0; g < 8; ++g) {
        const int reg = g * 2;
        const int dl = (reg & 3) + 8 * (reg >> 2) + 4 * hi;
        const int d = dh * 32 + dl;
        const uint32_t wv = pk_bf16(oa[reg] * inv, oa[reg + 1] * inv);
        const int byte = lq * 128 + ((((d >> 3) ^ (lq & 7))) << 4) + ((d & 7) << 1);
        *reinterpret_cast<uint32_t*>(reinterpret_cast<char*>(Os) + byte) = wv;
      }
    }
    if (NSPLIT == 2 && lane < 32)
      Lp[(size_t)(z * 32 + bh) * 2048 + q0 + lq] = l_;
#pragma unroll
    for (int it = 0; it < 4; ++it) {
      const int q = it * 8 + (lane >> 3);
      const int ch = lane & 7;
      bf16x8 ov = *reinterpret_cast<const bf16x8*>(
          reinterpret_cast<char*>(Os) + q * 128 + ((ch ^ (q & 7)) << 4));
      if constexpr (NSPLIT == 1) {
        const size_t gaddr = (((size_t)(b * S_LEN + q0 + q)) << 10) + h * 64 + ch * 8;
        *reinterpret_cast<bf16x8*>(Og + gaddr) = ov;
      } else {
        const size_t rowoff = ((size_t)((z * 32 + bh) * 2048 + q0 + q)) << 6;
        *reinterpret_cast<bf16x8*>(Op + rowoff + ch * 8) = ov;
      }
    }
  }
#undef STAGE
}

// ---------------- combine two KV-half bf16 partials -> bf16 Ob ----------------
__global__ void attn_combine(const bf16_t* __restrict__ Op, const float* __restrict__ Lp,
                             bf16_t* __restrict__ Ob) {
  const int gid = blockIdx.x * 256 + threadIdx.x;   // 65536 rows x 8 chunks of 8
  const int row = gid >> 3, ch = gid & 7;
  const bf16_t* o1 = Op + ((size_t)row << 6) + ch * 8;
  const bf16_t* o2 = o1 + (1u << 22);               // + 65536*64 elems
  const float inv = 1.f / (Lp[row] + Lp[(1u << 16) + row]);
  bf16x8 v1 = *reinterpret_cast<const bf16x8*>(o1);
  bf16x8 v2 = *reinterpret_cast<const bf16x8*>(o2);
  bf16x8 o;
#pragma unroll
  for (int i = 0; i < 8; ++i) o[i] = (bf16_t)(((float)v1[i] + (float)v2[i]) * inv);
  const int bh = row >> 11, s = row & 2047;
  const int b = bh >> 4, h = bh & 15;
  *reinterpret_cast<bf16x8*>(Ob + (((size_t)(b * S_LEN + s)) << 10) + h * 64 + ch * 8) = o;
}

// ---------------------------------------------------------------------------
extern "C" void kernel_launch(void* const* d_in, const int* in_sizes, int n_in,
                              void* d_out, int out_size, void* d_ws, size_t ws_size,
                              hipStream_t stream) {
  const float* x = (const float*)d_in[0];
  const float* Wq = (const float*)d_in[1];
  const float* bq = (const float*)d_in[2];
  const float* Wk = (const float*)d_in[3];
  const float* bk = (const float*)d_in[4];
  const float* Wv = (const float*)d_in[5];
  const float* bv = (const float*)d_in[6];
  const float* Wo = (const float*)d_in[7];
  const float* bo = (const float*)d_in[8];
  const float* qnw = (const float*)d_in[9];
  const float* qnb = (const float*)d_in[10];
  const float* knw = (const float*)d_in[11];
  const float* knb = (const float*)d_in[12];
  float* out = (float*)d_out;

  uint8_t* ws = (uint8_t*)d_ws;
  bf16_t* xb = (bf16_t*)(ws + 0);          // [4096][1024]      8388608
  bf16_t* Wb = (bf16_t*)(ws + 8388608);    // [3072][1024]      6291456
  bf16_t* Wob = (bf16_t*)(ws + 14680064);  // [1024][1024]      2097152
  bf16_t* Qb = (bf16_t*)(ws + 16777216);   // [32][2048][64]    8388608
  bf16_t* Kb = (bf16_t*)(ws + 25165824);   // [32][2048][64]    8388608
  bf16_t* Vt = (bf16_t*)(ws + 33554432);   // [32][64][2048]    8388608
  bf16_t* Ob = (bf16_t*)(ws + 41943040);   // [4096][1024]      8388608
  bf16_t* Opart = (bf16_t*)(ws + 50331648);// [2][65536][64]bf16 16777216
  float*  Lpart = (float*)(ws + 67108864); // [2][65536]   f32     524288
  const bool split = ws_size >= 67633152ull;

  cvt_all<<<8192, 256, 0, stream>>>(x, Wq, Wk, Wv, Wo, xb, Wb, Wob);

  gemm_qkv_ln<<<dim3(24, 32), 256, 0, stream>>>(xb, Wb, bq, bk, bv, qnw, qnb, knw, knb,
                                                Qb, Kb, Vt);
  if (split) {
    attn_kernel<2><<<dim3(16, 32, 2), 256, 0, stream>>>(Qb, Kb, Vt, Ob, Opart, Lpart);
    attn_combine<<<2048, 256, 0, stream>>>(Opart, Lpart, Ob);
  } else {
    attn_kernel<1><<<dim3(16, 32, 1), 256, 0, stream>>>(Qb, Kb, Vt, Ob, Opart, Lpart);
  }
  gemm_out<<<dim3(8, 64), 256, 0, stream>>>(Ob, Wob, bo, out);
}